// Round 3
// baseline (112.402 us; speedup 1.0000x reference)
//
#include <hip/hip_runtime.h>
#include <hip/hip_cooperative_groups.h>

namespace cg = cooperative_groups;

#define NB 2048   // rows (B)
#define NC 8192   // classes (C)
#define NP 8      // positives per row (P)
#define BLK 256
#define NBLOCKS 1024
#define RPB 2     // rows per block

__global__ __launch_bounds__(BLK) void mlce_fused_kernel(
    const float* __restrict__ pred,
    const int* __restrict__ labels,
    float* __restrict__ row_loss,
    float* __restrict__ out) {
    const int tid = threadIdx.x;
    const int lane = tid & 63;
    const int wid = tid >> 6;
    __shared__ float wsum[BLK / 64];
    __shared__ float s_all_sh;

#pragma unroll
    for (int r = 0; r < RPB; ++r) {
        const int row = blockIdx.x + r * NBLOCKS;

        // Gather this row's positive logits early (two dependent loads —
        // overlap their latency with the bulk row loads below).
        float plog = 0.f;
        if (tid < NP) {
            int lab = labels[row * NP + tid];
            plog = pred[(size_t)row * NC + lab];
        }

        const float4* rowp = reinterpret_cast<const float4*>(pred + (size_t)row * NC);
        float4 v[NC / 4 / BLK];
#pragma unroll
        for (int i = 0; i < NC / 4 / BLK; ++i) v[i] = rowp[tid + i * BLK];

        float a0 = 0.f, a1 = 0.f, a2 = 0.f, a3 = 0.f;
#pragma unroll
        for (int i = 0; i < NC / 4 / BLK; ++i) {
            a0 += __expf(v[i].x);
            a1 += __expf(v[i].y);
            a2 += __expf(v[i].z);
            a3 += __expf(v[i].w);
        }
        float partial = (a0 + a1) + (a2 + a3);
#pragma unroll
        for (int off = 32; off; off >>= 1)
            partial += __shfl_down(partial, off, 64);

        if (lane == 0) wsum[wid] = partial;
        __syncthreads();
        if (tid == 0) s_all_sh = (wsum[0] + wsum[1]) + (wsum[2] + wsum[3]);
        __syncthreads();

        // Threads 0..7 finish this row in parallel (butterfly over width 8).
        if (tid < NP) {
            float pe = __expf(plog);
            float s_pos = pe;
#pragma unroll
            for (int off = 4; off; off >>= 1) s_pos += __shfl_xor(s_pos, off, 8);
            const float s_neg = s_all_sh - s_pos;
            float term = __logf(s_neg + pe) - plog;
#pragma unroll
            for (int off = 4; off; off >>= 1) term += __shfl_xor(term, off, 8);
            if (tid == 0) row_loss[row] = term;
        }
        __syncthreads();   // wsum/s_all_sh reused next row iteration
    }

    cg::this_grid().sync();

    if (blockIdx.x == 0) {
        float s = 0.f;
#pragma unroll
        for (int i = 0; i < NB / BLK; ++i) s += row_loss[tid + i * BLK];
#pragma unroll
        for (int off = 32; off; off >>= 1)
            s += __shfl_down(s, off, 64);
        if (lane == 0) wsum[wid] = s;
        __syncthreads();
        if (tid == 0)
            out[0] = ((wsum[0] + wsum[1]) + (wsum[2] + wsum[3])) / (float)(NB * NP);
    }
}

extern "C" void kernel_launch(void* const* d_in, const int* in_sizes, int n_in,
                              void* d_out, int out_size, void* d_ws, size_t ws_size,
                              hipStream_t stream) {
    const float* pred = (const float*)d_in[0];
    const int* labels = (const int*)d_in[1];
    float* out = (float*)d_out;
    float* row_loss = (float*)d_ws;   // NB floats; every slot written before read

    void* args[] = {(void*)&pred, (void*)&labels, (void*)&row_loss, (void*)&out};
    hipLaunchCooperativeKernel((void*)mlce_fused_kernel, dim3(NBLOCKS), dim3(BLK),
                               args, 0, stream);
}

// Round 4
// 17.913 us; speedup vs baseline: 6.2748x; 6.2748x over previous
//
#include <hip/hip_runtime.h>

#define NB 2048   // rows (B)
#define NC 8192   // classes (C)
#define NP 8      // positives per row (P)
#define BLK 256

// Stage 1: one block per row. Sum exp over the row; threads 0..7 finish the
// per-row multi-label CE term in parallel and write row_loss[row].
__global__ __launch_bounds__(BLK) void mlce_row_kernel(
    const float* __restrict__ pred,
    const int* __restrict__ labels,
    float* __restrict__ row_loss) {
    const int row = blockIdx.x;
    const int tid = threadIdx.x;
    const int lane = tid & 63;
    const int wid = tid >> 6;

    // Positive-logit gather issued first; latency overlaps the bulk loads.
    float plog = 0.f;
    if (tid < NP) {
        int lab = labels[row * NP + tid];
        plog = pred[(size_t)row * NC + lab];
    }

    const float4* rowp = reinterpret_cast<const float4*>(pred + (size_t)row * NC);
    float4 v[NC / 4 / BLK];
#pragma unroll
    for (int i = 0; i < NC / 4 / BLK; ++i) v[i] = rowp[tid + i * BLK];

    float a0 = 0.f, a1 = 0.f, a2 = 0.f, a3 = 0.f;
#pragma unroll
    for (int i = 0; i < NC / 4 / BLK; ++i) {
        a0 += __expf(v[i].x);
        a1 += __expf(v[i].y);
        a2 += __expf(v[i].z);
        a3 += __expf(v[i].w);
    }
    float partial = (a0 + a1) + (a2 + a3);

#pragma unroll
    for (int off = 32; off; off >>= 1)
        partial += __shfl_down(partial, off, 64);

    __shared__ float wsum[BLK / 64];
    __shared__ float s_all_sh;
    if (lane == 0) wsum[wid] = partial;
    __syncthreads();
    if (tid == 0) s_all_sh = (wsum[0] + wsum[1]) + (wsum[2] + wsum[3]);
    __syncthreads();

    if (tid < NP) {
        float pe = __expf(plog);
        float s_pos = pe;
#pragma unroll
        for (int off = 4; off; off >>= 1) s_pos += __shfl_xor(s_pos, off, 8);
        const float s_neg = s_all_sh - s_pos;
        float term = __logf(s_neg + pe) - plog;
#pragma unroll
        for (int off = 4; off; off >>= 1) term += __shfl_xor(term, off, 8);
        if (tid == 0) row_loss[row] = term;
    }
}

// Stage 2: one wave reduces the 2048 per-row losses (float4 loads, shuffle
// only — no LDS, no __syncthreads).
__global__ __launch_bounds__(64) void mlce_reduce_kernel(
    const float* __restrict__ row_loss,
    float* __restrict__ out) {
    const int tid = threadIdx.x;
    const float4* rp = reinterpret_cast<const float4*>(row_loss);
    float s = 0.f;
#pragma unroll
    for (int i = 0; i < NB / 4 / 64; ++i) {
        float4 v = rp[tid + i * 64];
        s += (v.x + v.y) + (v.z + v.w);
    }
#pragma unroll
    for (int off = 32; off; off >>= 1)
        s += __shfl_down(s, off, 64);
    if (tid == 0) out[0] = s / (float)(NB * NP);
}

extern "C" void kernel_launch(void* const* d_in, const int* in_sizes, int n_in,
                              void* d_out, int out_size, void* d_ws, size_t ws_size,
                              hipStream_t stream) {
    const float* pred = (const float*)d_in[0];
    const int* labels = (const int*)d_in[1];
    float* out = (float*)d_out;
    float* row_loss = (float*)d_ws;   // NB floats; every slot written before read

    mlce_row_kernel<<<NB, BLK, 0, stream>>>(pred, labels, row_loss);
    mlce_reduce_kernel<<<1, 64, 0, stream>>>(row_loss, out);
}